// Round 4
// baseline (2185.426 us; speedup 1.0000x reference)
//
#include <hip/hip_runtime.h>

typedef unsigned int u32;
typedef unsigned long long u64;
typedef u32   v4u __attribute__((ext_vector_type(4)));
typedef float v4f __attribute__((ext_vector_type(4)));
typedef float v2f __attribute__((ext_vector_type(2)));

#define NN 100000
#define NE 3200000
#define DF 64
#define ALPHA 0.1f
#define BETA 0.9f
#define K_STEPS 10
#define NBKT 782              // ceil(NN/128) row buckets, 128 rows each
#define EPT 16                // edges per thread in bucket passes (round-0 verified)
#define CHUNK (256 * EPT)     // 4096 edges per block
#define NCHB ((NE + CHUNK - 1) / CHUNK)   // 782 chunks
#define NQB 25000             // node-blocks per quarter (4 nodes/block)
#define QSTRIDE 800000        // u32s per quarter table (NN*8)

// bf16 round-to-nearest-even -> 16-bit pattern
__device__ __forceinline__ u32 rne_bf16(float f) {
    u32 u = __float_as_uint(f);
    return (u + 0x7FFFu + ((u >> 16) & 1u)) >> 16;
}
__device__ __forceinline__ float bf_lo(u32 w) { return __uint_as_float(w << 16); }
__device__ __forceinline__ float bf_hi(u32 w) { return __uint_as_float(w & 0xFFFF0000u); }

// ---- A1: bucket histogram (LDS-privatized) ------------------------------
__global__ void bucket_hist(const int* __restrict__ row, int* __restrict__ bcnt) {
    __shared__ int s[NBKT];
    for (int i = threadIdx.x; i < NBKT; i += 256) s[i] = 0;
    __syncthreads();
    int base = blockIdx.x * CHUNK + threadIdx.x;
    #pragma unroll
    for (int j = 0; j < EPT; ++j) {
        int e = base + j * 256;
        if (e < NE) atomicAdd(&s[row[e] >> 7], 1);
    }
    __syncthreads();
    for (int i = threadIdx.x; i < NBKT; i += 256) {
        int v = s[i];
        if (v) atomicAdd(&bcnt[i], v);
    }
}

// ---- scan of 782 bucket counts -> bases + cursors (one block) -----------
__global__ void scan_buckets(const int* __restrict__ bcnt, int* __restrict__ bbase,
                             int* __restrict__ bcur) {
    __shared__ int s[1024];
    int i = threadIdx.x;
    int v = (i < NBKT) ? bcnt[i] : 0;
    s[i] = v;
    __syncthreads();
    for (int off = 1; off < 1024; off <<= 1) {
        int t = (i >= off) ? s[i - off] : 0;
        __syncthreads();
        s[i] += t;
        __syncthreads();
    }
    if (i < NBKT) { int b = s[i] - v; bbase[i] = b; bcur[i] = b; }
}

// ---- A2: scatter packed u64 entries into bucket regions -----------------
// entry = (row&127)<<32 | col<<15 | bf16(w)[14:0]
__global__ void bucket_scatter(const int* __restrict__ row, const int* __restrict__ col,
                               const float* __restrict__ w, int* __restrict__ bcur,
                               u64* __restrict__ e64) {
    __shared__ int scnt[NBKT];
    __shared__ int sbase[NBKT];
    for (int i = threadIdx.x; i < NBKT; i += 256) scnt[i] = 0;
    __syncthreads();
    int base = blockIdx.x * CHUNK + threadIdx.x;
    int rows[EPT];
    #pragma unroll
    for (int j = 0; j < EPT; ++j) {
        int e = base + j * 256;
        int r = (e < NE) ? row[e] : -1;
        rows[j] = r;
        if (r >= 0) atomicAdd(&scnt[r >> 7], 1);
    }
    __syncthreads();
    for (int i = threadIdx.x; i < NBKT; i += 256) {
        int c = scnt[i];
        sbase[i] = c ? atomicAdd(&bcur[i], c) : 0;
    }
    __syncthreads();
    for (int i = threadIdx.x; i < NBKT; i += 256) scnt[i] = 0;
    __syncthreads();
    #pragma unroll
    for (int j = 0; j < EPT; ++j) {
        int e = base + j * 256;
        int r = rows[j];
        if (r >= 0) {
            int b = r >> 7;
            int rank = atomicAdd(&scnt[b], 1);
            u32 cw = ((u32)col[e] << 15) | (rne_bf16(w[e]) & 0x7FFFu);
            e64[sbase[b] + rank] = ((u64)(r & 127) << 32) | cw;
        }
    }
}

// ---- B: per-bucket local CSR: rp + final packed u32 edges ---------------
__global__ void build_rows(const u64* __restrict__ e64, const int* __restrict__ bcnt,
                           const int* __restrict__ bbase, u32* __restrict__ edgesF,
                           int* __restrict__ rp) {
    __shared__ int rc[128];   // counts, then exclusive cursors
    __shared__ int rb[128];   // inclusive scan
    int b = blockIdx.x;
    int cnt = bcnt[b], base = bbase[b];
    if (threadIdx.x < 128) rc[threadIdx.x] = 0;
    __syncthreads();
    for (int e = threadIdx.x; e < cnt; e += 256)
        atomicAdd(&rc[(int)(e64[base + e] >> 32)], 1);
    __syncthreads();
    if (threadIdx.x < 128) rb[threadIdx.x] = rc[threadIdx.x];
    __syncthreads();
    for (int off = 1; off < 128; off <<= 1) {
        int t = (threadIdx.x < 128 && threadIdx.x >= off) ? rb[threadIdx.x - off] : 0;
        __syncthreads();
        if (threadIdx.x < 128) rb[threadIdx.x] += t;
        __syncthreads();
    }
    if (threadIdx.x < 128) {
        int r = b * 128 + threadIdx.x;
        if (r < NN) rp[r] = base + rb[threadIdx.x];      // global end offset
        rc[threadIdx.x] = rb[threadIdx.x] - rc[threadIdx.x];  // exclusive cursor
    }
    __syncthreads();
    for (int e = threadIdx.x; e < cnt; e += 256) {
        u64 ent = e64[base + e];
        int pos = atomicAdd(&rc[(int)(ent >> 32)], 1);
        edgesF[base + pos] = (u32)ent;
    }
}

// ---- x (f32) -> bf16 quarter tables: xq[q][node][8 u32] -----------------
// u32 fg of quarter q holds feats (q*16 + fg*2) [lo] and (+1) [hi]
__global__ void conv_xq(const float* __restrict__ x, u32* __restrict__ xq) {
    int t = blockIdx.x * blockDim.x + threadIdx.x;
    if (t >= NN * 4) return;
    int node = t >> 2;
    int q = t & 3;
    const float4* src = (const float4*)(x + (size_t)node * DF + q * 16);
    float4 a = src[0], b = src[1], c = src[2], d = src[3];
    uint4 o0, o1;
    o0.x = rne_bf16(a.x) | (rne_bf16(a.y) << 16);
    o0.y = rne_bf16(a.z) | (rne_bf16(a.w) << 16);
    o0.z = rne_bf16(b.x) | (rne_bf16(b.y) << 16);
    o0.w = rne_bf16(b.z) | (rne_bf16(b.w) << 16);
    o1.x = rne_bf16(c.x) | (rne_bf16(c.y) << 16);
    o1.y = rne_bf16(c.z) | (rne_bf16(c.w) << 16);
    o1.z = rne_bf16(d.x) | (rne_bf16(d.y) << 16);
    o1.w = rne_bf16(d.z) | (rne_bf16(d.w) << 16);
    u32* dst = xq + (size_t)q * QSTRIDE + ((size_t)node << 3);
    *(uint4*)(dst) = o0;
    *(uint4*)(dst + 4) = o1;
}

// ---- propagation: quarter-phased gather, one wave per (node, quarter) ---
// blockIdx.x in [0, 4*NQB): q = bx/NQB (dispatch-order -> temporal phases),
// each phase's gather target is one 3.2 MB quarter table (L2-resident).
__global__ __launch_bounds__(256) void
gather_q(const int* __restrict__ rp, const u32* __restrict__ edges,
         const u32* __restrict__ h, const u32* __restrict__ xq,
         u32* __restrict__ hn, float* __restrict__ outf, int final_step) {
    int bx = blockIdx.x;
    int q  = bx / NQB;
    int nb = bx - q * NQB;
    int lane = threadIdx.x & 63;
    int node = nb * 4 + (threadIdx.x >> 6);
    int slice = lane >> 3;        // 8 edge slices (same partition as before)
    int fg = lane & 7;            // u32 index within 32B quarter row

    const u32* hq = h + (size_t)q * QSTRIDE;

    int start = (node == 0) ? 0 : rp[node - 1];
    int end = rp[node];

    float a0 = 0.f, a1 = 0.f;
    #pragma unroll 4
    for (int e = start + slice; e < end; e += 8) {
        u32 ew = __builtin_nontemporal_load(edges + e);
        u32 c = ew >> 15;
        float wv = __uint_as_float((ew & 0x7FFFu) << 16);
        u32 hv = hq[((size_t)c << 3) + fg];
        a0 += wv * bf_lo(hv);
        a1 += wv * bf_hi(hv);
    }
    for (int m = 8; m <= 32; m <<= 1) {
        a0 += __shfl_xor(a0, m, 64);
        a1 += __shfl_xor(a1, m, 64);
    }
    if (slice == 0) {
        u32 xv = xq[(size_t)q * QSTRIDE + ((size_t)node << 3) + fg];
        float o0 = BETA * a0 + ALPHA * bf_lo(xv);
        float o1 = BETA * a1 + ALPHA * bf_hi(xv);
        if (!final_step) {
            u32 o = rne_bf16(o0) | (rne_bf16(o1) << 16);
            __builtin_nontemporal_store(o, hn + (size_t)q * QSTRIDE + ((size_t)node << 3) + fg);
        } else {
            v2f v; v.x = o0; v.y = o1;
            __builtin_nontemporal_store(v, (v2f*)(outf + (size_t)node * DF + q * 16 + fg * 2));
        }
    }
}

// ---- launch -------------------------------------------------------------

extern "C" void kernel_launch(void* const* d_in, const int* in_sizes, int n_in,
                              void* d_out, int out_size, void* d_ws, size_t ws_size,
                              hipStream_t stream) {
    const float* x    = (const float*)d_in[0];
    const int*   erow = (const int*)  d_in[1];
    const int*   ecol = (const int*)  d_in[2];
    const float* ew   = (const float*)d_in[3];
    float* out = (float*)d_out;

    char* ws = (char*)d_ws;
    u32* edgesF = (u32*)(ws);                     // 12,800,000 B final packed edges
    u32* xq     = (u32*)(ws + 12800000);          // 12,800,000 B bf16 x, quarter layout
    u32* hA     = (u32*)(ws + 25600000);          // 12,800,000 B quarter layout
    u32* hB     = (u32*)(ws + 38400000);          // 12,800,000 B quarter layout
    u64* e64    = (u64*)(ws + 25600000);          // 25,600,000 B — aliases hA+hB (dead before gathers)
    int* rp     = (int*)(ws + 51200000);          //    400,000 B
    int* bcnt   = (int*)(ws + 51600000);          //      3,128 B
    int* bbase  = (int*)(ws + 51604096);          //      3,128 B
    int* bcur   = (int*)(ws + 51608192);          //      3,128 B

    dim3 blk(256);
    dim3 gChunk(NCHB);                            // 782
    dim3 gConv((NN * 4 + 255) / 256);             // 1563
    dim3 gG(4 * NQB);                             // 100000 blocks: quarter-major

    (void)hipMemsetAsync(bcnt, 0, NBKT * sizeof(int), stream);
    bucket_hist<<<gChunk, blk, 0, stream>>>(erow, bcnt);
    scan_buckets<<<1, 1024, 0, stream>>>(bcnt, bbase, bcur);
    bucket_scatter<<<gChunk, blk, 0, stream>>>(erow, ecol, ew, bcur, e64);
    build_rows<<<NBKT, blk, 0, stream>>>(e64, bcnt, bbase, edgesF, rp);
    conv_xq<<<gConv, blk, 0, stream>>>(x, xq);

    // k=0 reads xq; then ping-pong hA/hB; k=9 writes f32 out
    for (int k = 0; k < K_STEPS; ++k) {
        const u32* src = (k == 0) ? xq : ((k & 1) ? hA : hB);
        u32* dst = (k & 1) ? hB : hA;
        int fin = (k == K_STEPS - 1);
        gather_q<<<gG, blk, 0, stream>>>(rp, edgesF, src, xq,
                                         fin ? nullptr : dst,
                                         fin ? out : nullptr, fin);
    }
}

// Round 5
// 895.162 us; speedup vs baseline: 2.4414x; 2.4414x over previous
//
#include <hip/hip_runtime.h>

typedef unsigned int u32;
typedef unsigned long long u64;
typedef unsigned char u8;
typedef u32   v4u __attribute__((ext_vector_type(4)));
typedef float v4f __attribute__((ext_vector_type(4)));

#define NN 100000
#define NE 3200000
#define DF 64
#define ALPHA 0.1f
#define BETA 0.9f
#define K_STEPS 10
#define NBKT 782              // ceil(NN/128) row buckets, 128 rows each
#define SLOTS 4608            // padded slots/bucket = mean 4092 + 8 sigma
#define EPT 16                // edges per thread in bucket passes (round-0 verified)
#define CHUNK (256 * EPT)     // 4096 edges per block
#define NCHB ((NE + CHUNK - 1) / CHUNK)   // 782 chunks

// bf16 round-to-nearest-even -> 16-bit pattern
__device__ __forceinline__ u32 rne_bf16(float f) {
    u32 u = __float_as_uint(f);
    return (u + 0x7FFFu + ((u >> 16) & 1u)) >> 16;
}
__device__ __forceinline__ float bf_lo(u32 w) { return __uint_as_float(w << 16); }
__device__ __forceinline__ float bf_hi(u32 w) { return __uint_as_float(w & 0xFFFF0000u); }

// ---- init padded bucket cursors ----------------------------------------
__global__ void init_cur(int* __restrict__ bcur) {
    int i = blockIdx.x * 256 + threadIdx.x;
    if (i < NBKT) bcur[i] = i * SLOTS;
}

// ---- A: scatter clustered entries into PADDED bucket regions ------------
// edgesT[pos] = col<<15 | bf16(w)[14:0] ; lr[pos] = row&127
__global__ void bucket_scatter(const int* __restrict__ row, const int* __restrict__ col,
                               const float* __restrict__ w, int* __restrict__ bcur,
                               u32* __restrict__ edgesT, u8* __restrict__ lr) {
    __shared__ int scnt[NBKT];
    __shared__ int sbase[NBKT];
    for (int i = threadIdx.x; i < NBKT; i += 256) scnt[i] = 0;
    __syncthreads();
    int base = blockIdx.x * CHUNK + threadIdx.x;
    int rows[EPT];
    #pragma unroll
    for (int j = 0; j < EPT; ++j) {
        int e = base + j * 256;
        int r = (e < NE) ? row[e] : -1;
        rows[j] = r;
        if (r >= 0) atomicAdd(&scnt[r >> 7], 1);
    }
    __syncthreads();
    for (int i = threadIdx.x; i < NBKT; i += 256) {
        int c = scnt[i];
        sbase[i] = c ? atomicAdd(&bcur[i], c) : 0;   // absolute padded position
    }
    __syncthreads();
    for (int i = threadIdx.x; i < NBKT; i += 256) scnt[i] = 0;
    __syncthreads();
    #pragma unroll
    for (int j = 0; j < EPT; ++j) {
        int e = base + j * 256;
        int r = rows[j];
        if (r >= 0) {
            int b = r >> 7;
            int rank = atomicAdd(&scnt[b], 1);
            int pos = sbase[b] + rank;
            if (pos < (b + 1) * SLOTS) {             // +8-sigma guard, ~never taken
                edgesT[pos] = ((u32)col[e] << 15) | (rne_bf16(w[e]) & 0x7FFFu);
                lr[pos] = (u8)(r & 127);
            }
        }
    }
}

// ---- scan: counts from final cursors -> dense bucket bases --------------
__global__ void scan_buckets(const int* __restrict__ bcur, int* __restrict__ bbase) {
    __shared__ int s[1024];
    int i = threadIdx.x;
    int v = 0;
    if (i < NBKT) {
        v = bcur[i] - i * SLOTS;
        if (v > SLOTS) v = SLOTS;
    }
    s[i] = v;
    __syncthreads();
    for (int off = 1; off < 1024; off <<= 1) {
        int t = (i >= off) ? s[i - off] : 0;
        __syncthreads();
        s[i] += t;
        __syncthreads();
    }
    if (i < NBKT) bbase[i] = s[i] - v;   // exclusive
}

// ---- B: per-bucket local CSR: compact padded -> dense edgesF + rp -------
__global__ void build_rows(const u32* __restrict__ edgesT, const u8* __restrict__ lr,
                           const int* __restrict__ bcur, const int* __restrict__ bbase,
                           u32* __restrict__ edgesF, int* __restrict__ rp) {
    __shared__ int rc[128];   // counts, then exclusive cursors
    __shared__ int rb[128];   // inclusive scan
    int b = blockIdx.x;
    int cnt = bcur[b] - b * SLOTS;
    if (cnt > SLOTS) cnt = SLOTS;
    int base = bbase[b];
    int tbase = b * SLOTS;
    if (threadIdx.x < 128) rc[threadIdx.x] = 0;
    __syncthreads();
    for (int e = threadIdx.x; e < cnt; e += 256)
        atomicAdd(&rc[lr[tbase + e]], 1);
    __syncthreads();
    if (threadIdx.x < 128) rb[threadIdx.x] = rc[threadIdx.x];
    __syncthreads();
    for (int off = 1; off < 128; off <<= 1) {
        int t = (threadIdx.x < 128 && threadIdx.x >= off) ? rb[threadIdx.x - off] : 0;
        __syncthreads();
        if (threadIdx.x < 128) rb[threadIdx.x] += t;
        __syncthreads();
    }
    if (threadIdx.x < 128) {
        int r = b * 128 + threadIdx.x;
        if (r < NN) rp[r] = base + rb[threadIdx.x];      // global end offset
        rc[threadIdx.x] = rb[threadIdx.x] - rc[threadIdx.x];  // exclusive cursor
    }
    __syncthreads();
    for (int e = threadIdx.x; e < cnt; e += 256) {
        int pos = atomicAdd(&rc[lr[tbase + e]], 1);
        edgesF[base + pos] = edgesT[tbase + e];
    }
}

// ---- x (f32) -> bf16 rows (h_0 and alpha-term) --------------------------
__global__ void conv_x(const float* __restrict__ x, u32* __restrict__ xb) {
    int t = blockIdx.x * blockDim.x + threadIdx.x;
    if (t >= NN * 8) return;
    const float4* src = (const float4*)(x + (size_t)t * 8);
    float4 a = src[0], b = src[1];
    uint4 o;
    o.x = rne_bf16(a.x) | (rne_bf16(a.y) << 16);
    o.y = rne_bf16(a.z) | (rne_bf16(a.w) << 16);
    o.z = rne_bf16(b.x) | (rne_bf16(b.y) << 16);
    o.w = rne_bf16(b.z) | (rne_bf16(b.w) << 16);
    *(uint4*)(xb + (size_t)t * 4) = o;
}

// ---- propagation: one wave per node, slice x feature-group lanes --------
__global__ __launch_bounds__(256) void
gather_step(const int* __restrict__ rp, const u32* __restrict__ edges,
            const u32* __restrict__ h, const u32* __restrict__ xb,
            u32* __restrict__ hn, float* __restrict__ outf, int final_step) {
    int lane = threadIdx.x & 63;
    int node = blockIdx.x * 4 + (threadIdx.x >> 6);
    int slice = lane >> 3;
    int fg = lane & 7;

    int start = (node == 0) ? 0 : rp[node - 1];
    int end = rp[node];

    float a0=0.f,a1=0.f,a2=0.f,a3=0.f,a4=0.f,a5=0.f,a6=0.f,a7=0.f;
    #pragma unroll 2
    for (int e = start + slice; e < end; e += 8) {
        u32 ew = __builtin_nontemporal_load(edges + e);
        u32 c = ew >> 15;
        float wv = __uint_as_float((ew & 0x7FFFu) << 16);
        const uint4 hv = *(const uint4*)(h + ((size_t)c << 5) + (fg << 2));
        a0 += wv * bf_lo(hv.x); a1 += wv * bf_hi(hv.x);
        a2 += wv * bf_lo(hv.y); a3 += wv * bf_hi(hv.y);
        a4 += wv * bf_lo(hv.z); a5 += wv * bf_hi(hv.z);
        a6 += wv * bf_lo(hv.w); a7 += wv * bf_hi(hv.w);
    }
    for (int m = 8; m <= 32; m <<= 1) {
        a0 += __shfl_xor(a0, m, 64); a1 += __shfl_xor(a1, m, 64);
        a2 += __shfl_xor(a2, m, 64); a3 += __shfl_xor(a3, m, 64);
        a4 += __shfl_xor(a4, m, 64); a5 += __shfl_xor(a5, m, 64);
        a6 += __shfl_xor(a6, m, 64); a7 += __shfl_xor(a7, m, 64);
    }
    uint4 xv = *(const uint4*)(xb + ((size_t)node << 5) + (fg << 2));
    float o0 = BETA * a0 + ALPHA * bf_lo(xv.x);
    float o1 = BETA * a1 + ALPHA * bf_hi(xv.x);
    float o2 = BETA * a2 + ALPHA * bf_lo(xv.y);
    float o3 = BETA * a3 + ALPHA * bf_hi(xv.y);
    float o4 = BETA * a4 + ALPHA * bf_lo(xv.z);
    float o5 = BETA * a5 + ALPHA * bf_hi(xv.z);
    float o6 = BETA * a6 + ALPHA * bf_lo(xv.w);
    float o7 = BETA * a7 + ALPHA * bf_hi(xv.w);

    if (!final_step) {
        if (slice == 0) {
            v4u o;
            o.x = rne_bf16(o0) | (rne_bf16(o1) << 16);
            o.y = rne_bf16(o2) | (rne_bf16(o3) << 16);
            o.z = rne_bf16(o4) | (rne_bf16(o5) << 16);
            o.w = rne_bf16(o6) | (rne_bf16(o7) << 16);
            __builtin_nontemporal_store(o, (v4u*)(hn + ((size_t)node << 5) + (fg << 2)));
        }
    } else {
        if (slice < 2) {
            v4f v;
            if (slice) { v.x = o4; v.y = o5; v.z = o6; v.w = o7; }
            else       { v.x = o0; v.y = o1; v.z = o2; v.w = o3; }
            __builtin_nontemporal_store(v, (v4f*)(outf + (size_t)node * DF + fg * 8 + slice * 4));
        }
    }
}

// ---- launch -------------------------------------------------------------

extern "C" void kernel_launch(void* const* d_in, const int* in_sizes, int n_in,
                              void* d_out, int out_size, void* d_ws, size_t ws_size,
                              hipStream_t stream) {
    const float* x    = (const float*)d_in[0];
    const int*   erow = (const int*)  d_in[1];
    const int*   ecol = (const int*)  d_in[2];
    const float* ew   = (const float*)d_in[3];
    float* out = (float*)d_out;

    char* ws = (char*)d_ws;
    u32* edgesF = (u32*)(ws);                     // 12,800,000 B final packed edges
    u32* xb     = (u32*)(ws + 12800000);          // 12,800,000 B bf16 x (= h_0)
    u32* hA     = (u32*)(ws + 25600000);          // 12,800,000 B
    u32* hB     = (u32*)(ws + 38400000);          // 12,800,000 B
    // preprocessing temps alias hA+hB (dead before k=0 gather rewrites them):
    u32* edgesT = (u32*)(ws + 25600000);          // 14,417,920 B padded cw entries
    u8*  lr     = (u8*) (ws + 40100000);          //  3,603,456 B padded localrow bytes
    int* rp     = (int*)(ws + 51200000);          //    400,000 B end offsets
    int* bcur   = (int*)(ws + 51600000);          //      3,128 B
    int* bbase  = (int*)(ws + 51604096);          //      3,128 B

    dim3 blk(256);
    dim3 gChunk(NCHB);                            // 782
    dim3 gConv((NN * 8 + 255) / 256);             // 3125
    dim3 gG(NN / 4);                              // 25000 blocks, 1 wave/node

    init_cur<<<dim3((NBKT + 255) / 256), blk, 0, stream>>>(bcur);
    bucket_scatter<<<gChunk, blk, 0, stream>>>(erow, ecol, ew, bcur, edgesT, lr);
    scan_buckets<<<1, 1024, 0, stream>>>(bcur, bbase);
    build_rows<<<NBKT, blk, 0, stream>>>(edgesT, lr, bcur, bbase, edgesF, rp);
    conv_x<<<gConv, blk, 0, stream>>>(x, xb);

    // k=0 reads xb; then ping-pong hA/hB; k=9 writes f32 out
    for (int k = 0; k < K_STEPS; ++k) {
        const u32* src = (k == 0) ? xb : ((k & 1) ? hA : hB);
        u32* dst = (k & 1) ? hB : hA;
        int fin = (k == K_STEPS - 1);
        gather_step<<<gG, blk, 0, stream>>>(rp, edgesF, src, xb,
                                            fin ? nullptr : dst,
                                            fin ? out : nullptr, fin);
    }
}

// Round 6
// 855.880 us; speedup vs baseline: 2.5534x; 1.0459x over previous
//
#include <hip/hip_runtime.h>

typedef unsigned int u32;
typedef unsigned long long u64;
typedef u32   v4u __attribute__((ext_vector_type(4)));
typedef float v4f __attribute__((ext_vector_type(4)));

#define NN 100000
#define NE 3200000
#define DF 64
#define ALPHA 0.1f
#define BETA 0.9f
#define K_STEPS 10
#define NBKT 782              // ceil(NN/128) row buckets, 128 rows each
#define EPT 16                // edges per thread in bucket passes (round-0 verified)
#define CHUNK (256 * EPT)     // 4096 edges per block
#define NCHB ((NE + CHUNK - 1) / CHUNK)   // 782 chunks
#define BRT 512               // build_rows threads (2x waves on fixed 782-block grid)

// bf16 round-to-nearest-even -> 16-bit pattern
__device__ __forceinline__ u32 rne_bf16(float f) {
    u32 u = __float_as_uint(f);
    return (u + 0x7FFFu + ((u >> 16) & 1u)) >> 16;
}
__device__ __forceinline__ float bf_lo(u32 w) { return __uint_as_float(w << 16); }
__device__ __forceinline__ float bf_hi(u32 w) { return __uint_as_float(w & 0xFFFF0000u); }

// ---- A1: bucket histogram (LDS-privatized) ------------------------------
__global__ void bucket_hist(const int* __restrict__ row, int* __restrict__ bcnt) {
    __shared__ int s[NBKT];
    for (int i = threadIdx.x; i < NBKT; i += 256) s[i] = 0;
    __syncthreads();
    int base = blockIdx.x * CHUNK + threadIdx.x;
    #pragma unroll
    for (int j = 0; j < EPT; ++j) {
        int e = base + j * 256;
        if (e < NE) atomicAdd(&s[row[e] >> 7], 1);
    }
    __syncthreads();
    for (int i = threadIdx.x; i < NBKT; i += 256) {
        int v = s[i];
        if (v) atomicAdd(&bcnt[i], v);
    }
}

// ---- scan of 782 bucket counts -> bases + cursors (one block) -----------
__global__ void scan_buckets(const int* __restrict__ bcnt, int* __restrict__ bbase,
                             int* __restrict__ bcur) {
    __shared__ int s[1024];
    int i = threadIdx.x;
    int v = (i < NBKT) ? bcnt[i] : 0;
    s[i] = v;
    __syncthreads();
    for (int off = 1; off < 1024; off <<= 1) {
        int t = (i >= off) ? s[i - off] : 0;
        __syncthreads();
        s[i] += t;
        __syncthreads();
    }
    if (i < NBKT) { int b = s[i] - v; bbase[i] = b; bcur[i] = b; }
}

// ---- A2: scatter packed u64 entries into bucket regions -----------------
// entry = (row&127)<<32 | col<<15 | bf16(w)[14:0]
// Ranks captured from the pass-1 counting atomic: ONE atomic round,
// TWO LDS sweeps, 3 barriers (round-0 had two rounds / three sweeps / 5).
__global__ void bucket_scatter(const int* __restrict__ row, const int* __restrict__ col,
                               const float* __restrict__ w, int* __restrict__ bcur,
                               u64* __restrict__ e64) {
    __shared__ int scnt[NBKT];
    __shared__ int sbase[NBKT];
    for (int i = threadIdx.x; i < NBKT; i += 256) scnt[i] = 0;
    __syncthreads();
    int base = blockIdx.x * CHUNK + threadIdx.x;
    int rows[EPT];
    int rank[EPT];
    #pragma unroll
    for (int j = 0; j < EPT; ++j) {
        int e = base + j * 256;
        int r = (e < NE) ? row[e] : -1;
        rows[j] = r;
        rank[j] = (r >= 0) ? atomicAdd(&scnt[r >> 7], 1) : 0;
    }
    __syncthreads();
    for (int i = threadIdx.x; i < NBKT; i += 256) {
        int c = scnt[i];
        sbase[i] = c ? atomicAdd(&bcur[i], c) : 0;
    }
    __syncthreads();
    #pragma unroll
    for (int j = 0; j < EPT; ++j) {
        int e = base + j * 256;
        int r = rows[j];
        if (r >= 0) {
            u32 cw = ((u32)col[e] << 15) | (rne_bf16(w[e]) & 0x7FFFu);
            e64[sbase[r >> 7] + rank[j]] = ((u64)(r & 127) << 32) | cw;
        }
    }
}

// ---- B: per-bucket local CSR: rp + final packed u32 edges ---------------
__global__ void build_rows(const u64* __restrict__ e64, const int* __restrict__ bcnt,
                           const int* __restrict__ bbase, u32* __restrict__ edgesF,
                           int* __restrict__ rp) {
    __shared__ int rc[128];   // counts, then exclusive cursors
    __shared__ int rb[128];   // inclusive scan
    int b = blockIdx.x;
    int cnt = bcnt[b], base = bbase[b];
    if (threadIdx.x < 128) rc[threadIdx.x] = 0;
    __syncthreads();
    for (int e = threadIdx.x; e < cnt; e += BRT)
        atomicAdd(&rc[(int)(e64[base + e] >> 32)], 1);
    __syncthreads();
    if (threadIdx.x < 128) rb[threadIdx.x] = rc[threadIdx.x];
    __syncthreads();
    for (int off = 1; off < 128; off <<= 1) {
        int t = (threadIdx.x < 128 && threadIdx.x >= off) ? rb[threadIdx.x - off] : 0;
        __syncthreads();
        if (threadIdx.x < 128) rb[threadIdx.x] += t;
        __syncthreads();
    }
    if (threadIdx.x < 128) {
        int r = b * 128 + threadIdx.x;
        if (r < NN) rp[r] = base + rb[threadIdx.x];      // global end offset
        rc[threadIdx.x] = rb[threadIdx.x] - rc[threadIdx.x];  // exclusive cursor
    }
    __syncthreads();
    for (int e = threadIdx.x; e < cnt; e += BRT) {
        u64 ent = e64[base + e];
        int pos = atomicAdd(&rc[(int)(ent >> 32)], 1);
        edgesF[base + pos] = (u32)ent;
    }
}

// ---- x (f32) -> bf16 rows (h_0 and alpha-term) --------------------------
__global__ void conv_x(const float* __restrict__ x, u32* __restrict__ xb) {
    int t = blockIdx.x * blockDim.x + threadIdx.x;
    if (t >= NN * 8) return;
    const float4* src = (const float4*)(x + (size_t)t * 8);
    float4 a = src[0], b = src[1];
    uint4 o;
    o.x = rne_bf16(a.x) | (rne_bf16(a.y) << 16);
    o.y = rne_bf16(a.z) | (rne_bf16(a.w) << 16);
    o.z = rne_bf16(b.x) | (rne_bf16(b.y) << 16);
    o.w = rne_bf16(b.z) | (rne_bf16(b.w) << 16);
    *(uint4*)(xb + (size_t)t * 4) = o;
}

// ---- propagation: one wave per node, slice x feature-group lanes --------
__global__ __launch_bounds__(256) void
gather_step(const int* __restrict__ rp, const u32* __restrict__ edges,
            const u32* __restrict__ h, const u32* __restrict__ xb,
            u32* __restrict__ hn, float* __restrict__ outf, int final_step) {
    int lane = threadIdx.x & 63;
    int node = blockIdx.x * 4 + (threadIdx.x >> 6);
    int slice = lane >> 3;
    int fg = lane & 7;

    int start = (node == 0) ? 0 : rp[node - 1];
    int end = rp[node];

    float a0=0.f,a1=0.f,a2=0.f,a3=0.f,a4=0.f,a5=0.f,a6=0.f,a7=0.f;
    #pragma unroll 2
    for (int e = start + slice; e < end; e += 8) {
        u32 ew = __builtin_nontemporal_load(edges + e);
        u32 c = ew >> 15;
        float wv = __uint_as_float((ew & 0x7FFFu) << 16);
        const uint4 hv = *(const uint4*)(h + ((size_t)c << 5) + (fg << 2));
        a0 += wv * bf_lo(hv.x); a1 += wv * bf_hi(hv.x);
        a2 += wv * bf_lo(hv.y); a3 += wv * bf_hi(hv.y);
        a4 += wv * bf_lo(hv.z); a5 += wv * bf_hi(hv.z);
        a6 += wv * bf_lo(hv.w); a7 += wv * bf_hi(hv.w);
    }
    for (int m = 8; m <= 32; m <<= 1) {
        a0 += __shfl_xor(a0, m, 64); a1 += __shfl_xor(a1, m, 64);
        a2 += __shfl_xor(a2, m, 64); a3 += __shfl_xor(a3, m, 64);
        a4 += __shfl_xor(a4, m, 64); a5 += __shfl_xor(a5, m, 64);
        a6 += __shfl_xor(a6, m, 64); a7 += __shfl_xor(a7, m, 64);
    }
    uint4 xv = *(const uint4*)(xb + ((size_t)node << 5) + (fg << 2));
    float o0 = BETA * a0 + ALPHA * bf_lo(xv.x);
    float o1 = BETA * a1 + ALPHA * bf_hi(xv.x);
    float o2 = BETA * a2 + ALPHA * bf_lo(xv.y);
    float o3 = BETA * a3 + ALPHA * bf_hi(xv.y);
    float o4 = BETA * a4 + ALPHA * bf_lo(xv.z);
    float o5 = BETA * a5 + ALPHA * bf_hi(xv.z);
    float o6 = BETA * a6 + ALPHA * bf_lo(xv.w);
    float o7 = BETA * a7 + ALPHA * bf_hi(xv.w);

    if (!final_step) {
        if (slice == 0) {
            v4u o;
            o.x = rne_bf16(o0) | (rne_bf16(o1) << 16);
            o.y = rne_bf16(o2) | (rne_bf16(o3) << 16);
            o.z = rne_bf16(o4) | (rne_bf16(o5) << 16);
            o.w = rne_bf16(o6) | (rne_bf16(o7) << 16);
            __builtin_nontemporal_store(o, (v4u*)(hn + ((size_t)node << 5) + (fg << 2)));
        }
    } else {
        if (slice < 2) {
            v4f v;
            if (slice) { v.x = o4; v.y = o5; v.z = o6; v.w = o7; }
            else       { v.x = o0; v.y = o1; v.z = o2; v.w = o3; }
            __builtin_nontemporal_store(v, (v4f*)(outf + (size_t)node * DF + fg * 8 + slice * 4));
        }
    }
}

// ---- launch -------------------------------------------------------------

extern "C" void kernel_launch(void* const* d_in, const int* in_sizes, int n_in,
                              void* d_out, int out_size, void* d_ws, size_t ws_size,
                              hipStream_t stream) {
    const float* x    = (const float*)d_in[0];
    const int*   erow = (const int*)  d_in[1];
    const int*   ecol = (const int*)  d_in[2];
    const float* ew   = (const float*)d_in[3];
    float* out = (float*)d_out;

    char* ws = (char*)d_ws;
    u32* edgesF = (u32*)(ws);                     // 12,800,000 B final packed edges
    u32* xb     = (u32*)(ws + 12800000);          // 12,800,000 B bf16 x (= h_0)
    u32* hA     = (u32*)(ws + 25600000);          // 12,800,000 B
    u32* hB     = (u32*)(ws + 38400000);          // 12,800,000 B
    u64* e64    = (u64*)(ws + 25600000);          // 25,600,000 B — aliases hA+hB (dead before gathers)
    int* rp     = (int*)(ws + 51200000);          //    400,000 B
    int* bcnt   = (int*)(ws + 51600000);          //      3,128 B
    int* bbase  = (int*)(ws + 51604096);          //      3,128 B
    int* bcur   = (int*)(ws + 51608192);          //      3,128 B

    dim3 blk(256);
    dim3 gChunk(NCHB);                            // 782
    dim3 gConv((NN * 8 + 255) / 256);             // 3125
    dim3 gG(NN / 4);                              // 25000 blocks, 1 wave/node

    (void)hipMemsetAsync(bcnt, 0, NBKT * sizeof(int), stream);
    bucket_hist<<<gChunk, blk, 0, stream>>>(erow, bcnt);
    scan_buckets<<<1, 1024, 0, stream>>>(bcnt, bbase, bcur);
    bucket_scatter<<<gChunk, blk, 0, stream>>>(erow, ecol, ew, bcur, e64);
    build_rows<<<NBKT, dim3(BRT), 0, stream>>>(e64, bcnt, bbase, edgesF, rp);
    conv_x<<<gConv, blk, 0, stream>>>(x, xb);

    // k=0 reads xb; then ping-pong hA/hB; k=9 writes f32 out
    for (int k = 0; k < K_STEPS; ++k) {
        const u32* src = (k == 0) ? xb : ((k & 1) ? hA : hB);
        u32* dst = (k & 1) ? hB : hA;
        int fin = (k == K_STEPS - 1);
        gather_step<<<gG, blk, 0, stream>>>(rp, edgesF, src, xb,
                                            fin ? nullptr : dst,
                                            fin ? out : nullptr, fin);
    }
}

// Round 7
// 834.006 us; speedup vs baseline: 2.6204x; 1.0262x over previous
//
#include <hip/hip_runtime.h>

typedef unsigned int u32;
typedef unsigned long long u64;
typedef u32   v4u __attribute__((ext_vector_type(4)));
typedef float v4f __attribute__((ext_vector_type(4)));

#define NN 100000
#define NE 3200000
#define DF 64
#define ALPHA 0.1f
#define BETA 0.9f
#define K_STEPS 10
#define NBKT 782              // ceil(NN/128) row buckets, 128 rows each
#define EPT 32                // edges per thread in bucket passes (EPT ladder: 8=114, 16=87, 32=?)
#define CHUNK (256 * EPT)     // 8192 edges per block
#define NCHB ((NE + CHUNK - 1) / CHUNK)   // 391 chunks
#define BRT 512               // build_rows threads (2x waves on fixed 782-block grid)

// bf16 round-to-nearest-even -> 16-bit pattern
__device__ __forceinline__ u32 rne_bf16(float f) {
    u32 u = __float_as_uint(f);
    return (u + 0x7FFFu + ((u >> 16) & 1u)) >> 16;
}
__device__ __forceinline__ float bf_lo(u32 w) { return __uint_as_float(w << 16); }
__device__ __forceinline__ float bf_hi(u32 w) { return __uint_as_float(w & 0xFFFF0000u); }

// ---- A1: bucket histogram (LDS-privatized) ------------------------------
__global__ void bucket_hist(const int* __restrict__ row, int* __restrict__ bcnt) {
    __shared__ int s[NBKT];
    for (int i = threadIdx.x; i < NBKT; i += 256) s[i] = 0;
    __syncthreads();
    int base = blockIdx.x * CHUNK + threadIdx.x;
    #pragma unroll
    for (int j = 0; j < EPT; ++j) {
        int e = base + j * 256;
        if (e < NE) atomicAdd(&s[row[e] >> 7], 1);
    }
    __syncthreads();
    for (int i = threadIdx.x; i < NBKT; i += 256) {
        int v = s[i];
        if (v) atomicAdd(&bcnt[i], v);
    }
}

// ---- scan of 782 bucket counts -> bases + cursors (one block) -----------
__global__ void scan_buckets(const int* __restrict__ bcnt, int* __restrict__ bbase,
                             int* __restrict__ bcur) {
    __shared__ int s[1024];
    int i = threadIdx.x;
    int v = (i < NBKT) ? bcnt[i] : 0;
    s[i] = v;
    __syncthreads();
    for (int off = 1; off < 1024; off <<= 1) {
        int t = (i >= off) ? s[i - off] : 0;
        __syncthreads();
        s[i] += t;
        __syncthreads();
    }
    if (i < NBKT) { int b = s[i] - v; bbase[i] = b; bcur[i] = b; }
}

// ---- A2: scatter packed u64 entries into bucket regions -----------------
// entry = (row&127)<<32 | col<<15 | bf16(w)[14:0]
// Ranks captured from the pass-1 counting atomic (one atomic round);
// row[e] re-read in pass 2 (L1/L2-hot) to keep VGPR count low at EPT=32.
__global__ void bucket_scatter(const int* __restrict__ row, const int* __restrict__ col,
                               const float* __restrict__ w, int* __restrict__ bcur,
                               u64* __restrict__ e64) {
    __shared__ int scnt[NBKT];
    __shared__ int sbase[NBKT];
    for (int i = threadIdx.x; i < NBKT; i += 256) scnt[i] = 0;
    __syncthreads();
    int base = blockIdx.x * CHUNK + threadIdx.x;
    int rank[EPT];
    #pragma unroll
    for (int j = 0; j < EPT; ++j) {
        int e = base + j * 256;
        rank[j] = (e < NE) ? atomicAdd(&scnt[row[e] >> 7], 1) : 0;
    }
    __syncthreads();
    for (int i = threadIdx.x; i < NBKT; i += 256) {
        int c = scnt[i];
        sbase[i] = c ? atomicAdd(&bcur[i], c) : 0;
    }
    __syncthreads();
    #pragma unroll
    for (int j = 0; j < EPT; ++j) {
        int e = base + j * 256;
        if (e < NE) {
            int r = row[e];                      // re-read: cache-hot
            u32 cw = ((u32)col[e] << 15) | (rne_bf16(w[e]) & 0x7FFFu);
            e64[sbase[r >> 7] + rank[j]] = ((u64)(r & 127) << 32) | cw;
        }
    }
}

// ---- B: per-bucket local CSR: rp + final packed u32 edges ---------------
__global__ void build_rows(const u64* __restrict__ e64, const int* __restrict__ bcnt,
                           const int* __restrict__ bbase, u32* __restrict__ edgesF,
                           int* __restrict__ rp) {
    __shared__ int rc[128];   // counts, then exclusive cursors
    __shared__ int rb[128];   // inclusive scan
    int b = blockIdx.x;
    int cnt = bcnt[b], base = bbase[b];
    if (threadIdx.x < 128) rc[threadIdx.x] = 0;
    __syncthreads();
    for (int e = threadIdx.x; e < cnt; e += BRT)
        atomicAdd(&rc[(int)(e64[base + e] >> 32)], 1);
    __syncthreads();
    if (threadIdx.x < 128) rb[threadIdx.x] = rc[threadIdx.x];
    __syncthreads();
    for (int off = 1; off < 128; off <<= 1) {
        int t = (threadIdx.x < 128 && threadIdx.x >= off) ? rb[threadIdx.x - off] : 0;
        __syncthreads();
        if (threadIdx.x < 128) rb[threadIdx.x] += t;
        __syncthreads();
    }
    if (threadIdx.x < 128) {
        int r = b * 128 + threadIdx.x;
        if (r < NN) rp[r] = base + rb[threadIdx.x];      // global end offset
        rc[threadIdx.x] = rb[threadIdx.x] - rc[threadIdx.x];  // exclusive cursor
    }
    __syncthreads();
    for (int e = threadIdx.x; e < cnt; e += BRT) {
        u64 ent = e64[base + e];
        int pos = atomicAdd(&rc[(int)(ent >> 32)], 1);
        edgesF[base + pos] = (u32)ent;
    }
}

// ---- x (f32) -> bf16 rows (h_0 and alpha-term) --------------------------
__global__ void conv_x(const float* __restrict__ x, u32* __restrict__ xb) {
    int t = blockIdx.x * blockDim.x + threadIdx.x;
    if (t >= NN * 8) return;
    const float4* src = (const float4*)(x + (size_t)t * 8);
    float4 a = src[0], b = src[1];
    uint4 o;
    o.x = rne_bf16(a.x) | (rne_bf16(a.y) << 16);
    o.y = rne_bf16(a.z) | (rne_bf16(a.w) << 16);
    o.z = rne_bf16(b.x) | (rne_bf16(b.y) << 16);
    o.w = rne_bf16(b.z) | (rne_bf16(b.w) << 16);
    *(uint4*)(xb + (size_t)t * 4) = o;
}

// ---- propagation: one wave per node, slice x feature-group lanes --------
__global__ __launch_bounds__(256) void
gather_step(const int* __restrict__ rp, const u32* __restrict__ edges,
            const u32* __restrict__ h, const u32* __restrict__ xb,
            u32* __restrict__ hn, float* __restrict__ outf, int final_step) {
    int lane = threadIdx.x & 63;
    int node = blockIdx.x * 4 + (threadIdx.x >> 6);
    int slice = lane >> 3;
    int fg = lane & 7;

    int start = (node == 0) ? 0 : rp[node - 1];
    int end = rp[node];

    float a0=0.f,a1=0.f,a2=0.f,a3=0.f,a4=0.f,a5=0.f,a6=0.f,a7=0.f;
    #pragma unroll 2
    for (int e = start + slice; e < end; e += 8) {
        u32 ew = __builtin_nontemporal_load(edges + e);
        u32 c = ew >> 15;
        float wv = __uint_as_float((ew & 0x7FFFu) << 16);
        const uint4 hv = *(const uint4*)(h + ((size_t)c << 5) + (fg << 2));
        a0 += wv * bf_lo(hv.x); a1 += wv * bf_hi(hv.x);
        a2 += wv * bf_lo(hv.y); a3 += wv * bf_hi(hv.y);
        a4 += wv * bf_lo(hv.z); a5 += wv * bf_hi(hv.z);
        a6 += wv * bf_lo(hv.w); a7 += wv * bf_hi(hv.w);
    }
    for (int m = 8; m <= 32; m <<= 1) {
        a0 += __shfl_xor(a0, m, 64); a1 += __shfl_xor(a1, m, 64);
        a2 += __shfl_xor(a2, m, 64); a3 += __shfl_xor(a3, m, 64);
        a4 += __shfl_xor(a4, m, 64); a5 += __shfl_xor(a5, m, 64);
        a6 += __shfl_xor(a6, m, 64); a7 += __shfl_xor(a7, m, 64);
    }
    uint4 xv = *(const uint4*)(xb + ((size_t)node << 5) + (fg << 2));
    float o0 = BETA * a0 + ALPHA * bf_lo(xv.x);
    float o1 = BETA * a1 + ALPHA * bf_hi(xv.x);
    float o2 = BETA * a2 + ALPHA * bf_lo(xv.y);
    float o3 = BETA * a3 + ALPHA * bf_hi(xv.y);
    float o4 = BETA * a4 + ALPHA * bf_lo(xv.z);
    float o5 = BETA * a5 + ALPHA * bf_hi(xv.z);
    float o6 = BETA * a6 + ALPHA * bf_lo(xv.w);
    float o7 = BETA * a7 + ALPHA * bf_hi(xv.w);

    if (!final_step) {
        if (slice == 0) {
            v4u o;
            o.x = rne_bf16(o0) | (rne_bf16(o1) << 16);
            o.y = rne_bf16(o2) | (rne_bf16(o3) << 16);
            o.z = rne_bf16(o4) | (rne_bf16(o5) << 16);
            o.w = rne_bf16(o6) | (rne_bf16(o7) << 16);
            __builtin_nontemporal_store(o, (v4u*)(hn + ((size_t)node << 5) + (fg << 2)));
        }
    } else {
        if (slice < 2) {
            v4f v;
            if (slice) { v.x = o4; v.y = o5; v.z = o6; v.w = o7; }
            else       { v.x = o0; v.y = o1; v.z = o2; v.w = o3; }
            __builtin_nontemporal_store(v, (v4f*)(outf + (size_t)node * DF + fg * 8 + slice * 4));
        }
    }
}

// ---- launch -------------------------------------------------------------

extern "C" void kernel_launch(void* const* d_in, const int* in_sizes, int n_in,
                              void* d_out, int out_size, void* d_ws, size_t ws_size,
                              hipStream_t stream) {
    const float* x    = (const float*)d_in[0];
    const int*   erow = (const int*)  d_in[1];
    const int*   ecol = (const int*)  d_in[2];
    const float* ew   = (const float*)d_in[3];
    float* out = (float*)d_out;

    char* ws = (char*)d_ws;
    u32* edgesF = (u32*)(ws);                     // 12,800,000 B final packed edges
    u32* xb     = (u32*)(ws + 12800000);          // 12,800,000 B bf16 x (= h_0)
    u32* hA     = (u32*)(ws + 25600000);          // 12,800,000 B
    u32* hB     = (u32*)(ws + 38400000);          // 12,800,000 B
    u64* e64    = (u64*)(ws + 25600000);          // 25,600,000 B — aliases hA+hB (dead before gathers)
    int* rp     = (int*)(ws + 51200000);          //    400,000 B
    int* bcnt   = (int*)(ws + 51600000);          //      3,128 B
    int* bbase  = (int*)(ws + 51604096);          //      3,128 B
    int* bcur   = (int*)(ws + 51608192);          //      3,128 B

    dim3 blk(256);
    dim3 gChunk(NCHB);                            // 391
    dim3 gConv((NN * 8 + 255) / 256);             // 3125
    dim3 gG(NN / 4);                              // 25000 blocks, 1 wave/node

    (void)hipMemsetAsync(bcnt, 0, NBKT * sizeof(int), stream);
    bucket_hist<<<gChunk, blk, 0, stream>>>(erow, bcnt);
    scan_buckets<<<1, 1024, 0, stream>>>(bcnt, bbase, bcur);
    bucket_scatter<<<gChunk, blk, 0, stream>>>(erow, ecol, ew, bcur, e64);
    build_rows<<<NBKT, dim3(BRT), 0, stream>>>(e64, bcnt, bbase, edgesF, rp);
    conv_x<<<gConv, blk, 0, stream>>>(x, xb);

    // k=0 reads xb; then ping-pong hA/hB; k=9 writes f32 out
    for (int k = 0; k < K_STEPS; ++k) {
        const u32* src = (k == 0) ? xb : ((k & 1) ? hA : hB);
        u32* dst = (k & 1) ? hB : hA;
        int fin = (k == K_STEPS - 1);
        gather_step<<<gG, blk, 0, stream>>>(rp, edgesF, src, xb,
                                            fin ? nullptr : dst,
                                            fin ? out : nullptr, fin);
    }
}

// Round 8
// 825.847 us; speedup vs baseline: 2.6463x; 1.0099x over previous
//
#include <hip/hip_runtime.h>

typedef unsigned int u32;
typedef unsigned long long u64;
typedef u32   v4u __attribute__((ext_vector_type(4)));
typedef float v4f __attribute__((ext_vector_type(4)));

#define NN 100000
#define NE 3200000
#define DF 64
#define ALPHA 0.1f
#define BETA 0.9f
#define K_STEPS 10
#define NBKT 782              // ceil(NN/128) row buckets, 128 rows each
#define SLOTS 4608            // padded slots/bucket: mean 4092 + 8 sigma, = 9*512
#define EPT 32                // edges per thread (ladder: 8=114, 16=87, 32=80 us)
#define CHUNK (256 * EPT)     // 8192 edges per block
#define NCHB ((NE + CHUNK - 1) / CHUNK)   // 391 chunks
#define BRT 512               // build_rows threads; 9*BRT == SLOTS exactly

// bf16 round-to-nearest-even -> 16-bit pattern
__device__ __forceinline__ u32 rne_bf16(float f) {
    u32 u = __float_as_uint(f);
    return (u + 0x7FFFu + ((u >> 16) & 1u)) >> 16;
}
__device__ __forceinline__ float bf_lo(u32 w) { return __uint_as_float(w << 16); }
__device__ __forceinline__ float bf_hi(u32 w) { return __uint_as_float(w & 0xFFFF0000u); }

// ---- init padded bucket cursors (replaces hist + memset) ----------------
__global__ void init_cur(int* __restrict__ bcur) {
    int i = blockIdx.x * 256 + threadIdx.x;
    if (i < NBKT) bcur[i] = i * SLOTS;
}

// ---- A: scatter packed u64 entries into PADDED bucket regions -----------
// entry = (row&127)<<32 | col<<15 | bf16(w)[14:0]
// Rank captured from pass-1 counting atomic; row re-read in pass 2 (cache-hot).
__global__ void bucket_scatter(const int* __restrict__ row, const int* __restrict__ col,
                               const float* __restrict__ w, int* __restrict__ bcur,
                               u64* __restrict__ e64) {
    __shared__ int scnt[NBKT];
    __shared__ int sbase[NBKT];
    for (int i = threadIdx.x; i < NBKT; i += 256) scnt[i] = 0;
    __syncthreads();
    int base = blockIdx.x * CHUNK + threadIdx.x;
    int rank[EPT];
    #pragma unroll
    for (int j = 0; j < EPT; ++j) {
        int e = base + j * 256;
        rank[j] = (e < NE) ? atomicAdd(&scnt[row[e] >> 7], 1) : 0;
    }
    __syncthreads();
    for (int i = threadIdx.x; i < NBKT; i += 256) {
        int c = scnt[i];
        sbase[i] = c ? atomicAdd(&bcur[i], c) : 0;   // absolute padded position
    }
    __syncthreads();
    #pragma unroll
    for (int j = 0; j < EPT; ++j) {
        int e = base + j * 256;
        if (e < NE) {
            int r = row[e];                          // re-read: cache-hot
            int b = r >> 7;
            int pos = sbase[b] + rank[j];
            if (pos < (b + 1) * SLOTS) {             // +8-sigma guard, ~never taken
                u32 cw = ((u32)col[e] << 15) | (rne_bf16(w[e]) & 0x7FFFu);
                e64[pos] = ((u64)(r & 127) << 32) | cw;
            }
        }
    }
}

// ---- scan: counts from final cursors -> dense bucket bases --------------
__global__ void scan_buckets(const int* __restrict__ bcur, int* __restrict__ bbase) {
    __shared__ int s[1024];
    int i = threadIdx.x;
    int v = 0;
    if (i < NBKT) {
        v = bcur[i] - i * SLOTS;
        if (v > SLOTS) v = SLOTS;
    }
    s[i] = v;
    __syncthreads();
    for (int off = 1; off < 1024; off <<= 1) {
        int t = (i >= off) ? s[i - off] : 0;
        __syncthreads();
        s[i] += t;
        __syncthreads();
    }
    if (i < NBKT) bbase[i] = s[i] - v;   // exclusive
}

// ---- B: per-bucket local CSR: padded -> dense edgesF + rp ---------------
// Rank-capture: pass-1 counting atomic yields ranks; pass-3 is atomic-free.
__global__ __launch_bounds__(BRT) void
build_rows(const u64* __restrict__ e64, const int* __restrict__ bcur,
           const int* __restrict__ bbase, u32* __restrict__ edgesF,
           int* __restrict__ rp) {
    __shared__ int rc[128];   // counts -> exclusive bases
    __shared__ int rb[128];   // inclusive scan
    int b = blockIdx.x;
    int cnt = bcur[b] - b * SLOTS;
    if (cnt > SLOTS) cnt = SLOTS;
    int base = bbase[b];
    const u64* src = e64 + (size_t)b * SLOTS;
    if (threadIdx.x < 128) rc[threadIdx.x] = 0;
    __syncthreads();
    u64 ent[9];
    int rk[9];
    #pragma unroll
    for (int it = 0; it < 9; ++it) {               // 9*512 = 4608 = SLOTS
        int e = threadIdx.x + it * BRT;
        if (e < cnt) {
            ent[it] = src[e];
            rk[it] = atomicAdd(&rc[(int)(ent[it] >> 32)], 1);
        }
    }
    __syncthreads();
    int myc = (threadIdx.x < 128) ? rc[threadIdx.x] : 0;
    if (threadIdx.x < 128) rb[threadIdx.x] = myc;
    __syncthreads();
    for (int off = 1; off < 128; off <<= 1) {
        int t = (threadIdx.x < 128 && threadIdx.x >= off) ? rb[threadIdx.x - off] : 0;
        __syncthreads();
        if (threadIdx.x < 128) rb[threadIdx.x] += t;
        __syncthreads();
    }
    if (threadIdx.x < 128) {
        int r = b * 128 + threadIdx.x;
        if (r < NN) rp[r] = base + rb[threadIdx.x];      // global end offset
        rc[threadIdx.x] = rb[threadIdx.x] - myc;         // exclusive base
    }
    __syncthreads();
    #pragma unroll
    for (int it = 0; it < 9; ++it) {
        int e = threadIdx.x + it * BRT;
        if (e < cnt)
            edgesF[base + rc[(int)(ent[it] >> 32)] + rk[it]] = (u32)ent[it];
    }
}

// ---- x (f32) -> bf16 rows (h_0 and alpha-term); runs AFTER build_rows ---
__global__ void conv_x(const float* __restrict__ x, u32* __restrict__ xb) {
    int t = blockIdx.x * blockDim.x + threadIdx.x;
    if (t >= NN * 8) return;
    const float4* src = (const float4*)(x + (size_t)t * 8);
    float4 a = src[0], b = src[1];
    uint4 o;
    o.x = rne_bf16(a.x) | (rne_bf16(a.y) << 16);
    o.y = rne_bf16(a.z) | (rne_bf16(a.w) << 16);
    o.z = rne_bf16(b.x) | (rne_bf16(b.y) << 16);
    o.w = rne_bf16(b.z) | (rne_bf16(b.w) << 16);
    *(uint4*)(xb + (size_t)t * 4) = o;
}

// ---- propagation: one wave per node, slice x feature-group lanes --------
__global__ __launch_bounds__(256) void
gather_step(const int* __restrict__ rp, const u32* __restrict__ edges,
            const u32* __restrict__ h, const u32* __restrict__ xb,
            u32* __restrict__ hn, float* __restrict__ outf, int final_step) {
    int lane = threadIdx.x & 63;
    int node = blockIdx.x * 4 + (threadIdx.x >> 6);
    int slice = lane >> 3;
    int fg = lane & 7;

    int start = (node == 0) ? 0 : rp[node - 1];
    int end = rp[node];

    float a0=0.f,a1=0.f,a2=0.f,a3=0.f,a4=0.f,a5=0.f,a6=0.f,a7=0.f;
    #pragma unroll 2
    for (int e = start + slice; e < end; e += 8) {
        u32 ew = __builtin_nontemporal_load(edges + e);
        u32 c = ew >> 15;
        float wv = __uint_as_float((ew & 0x7FFFu) << 16);
        const uint4 hv = *(const uint4*)(h + ((size_t)c << 5) + (fg << 2));
        a0 += wv * bf_lo(hv.x); a1 += wv * bf_hi(hv.x);
        a2 += wv * bf_lo(hv.y); a3 += wv * bf_hi(hv.y);
        a4 += wv * bf_lo(hv.z); a5 += wv * bf_hi(hv.z);
        a6 += wv * bf_lo(hv.w); a7 += wv * bf_hi(hv.w);
    }
    for (int m = 8; m <= 32; m <<= 1) {
        a0 += __shfl_xor(a0, m, 64); a1 += __shfl_xor(a1, m, 64);
        a2 += __shfl_xor(a2, m, 64); a3 += __shfl_xor(a3, m, 64);
        a4 += __shfl_xor(a4, m, 64); a5 += __shfl_xor(a5, m, 64);
        a6 += __shfl_xor(a6, m, 64); a7 += __shfl_xor(a7, m, 64);
    }
    uint4 xv = *(const uint4*)(xb + ((size_t)node << 5) + (fg << 2));
    float o0 = BETA * a0 + ALPHA * bf_lo(xv.x);
    float o1 = BETA * a1 + ALPHA * bf_hi(xv.x);
    float o2 = BETA * a2 + ALPHA * bf_lo(xv.y);
    float o3 = BETA * a3 + ALPHA * bf_hi(xv.y);
    float o4 = BETA * a4 + ALPHA * bf_lo(xv.z);
    float o5 = BETA * a5 + ALPHA * bf_hi(xv.z);
    float o6 = BETA * a6 + ALPHA * bf_lo(xv.w);
    float o7 = BETA * a7 + ALPHA * bf_hi(xv.w);

    if (!final_step) {
        if (slice == 0) {
            v4u o;
            o.x = rne_bf16(o0) | (rne_bf16(o1) << 16);
            o.y = rne_bf16(o2) | (rne_bf16(o3) << 16);
            o.z = rne_bf16(o4) | (rne_bf16(o5) << 16);
            o.w = rne_bf16(o6) | (rne_bf16(o7) << 16);
            __builtin_nontemporal_store(o, (v4u*)(hn + ((size_t)node << 5) + (fg << 2)));
        }
    } else {
        if (slice < 2) {
            v4f v;
            if (slice) { v.x = o4; v.y = o5; v.z = o6; v.w = o7; }
            else       { v.x = o0; v.y = o1; v.z = o2; v.w = o3; }
            __builtin_nontemporal_store(v, (v4f*)(outf + (size_t)node * DF + fg * 8 + slice * 4));
        }
    }
}

// ---- launch -------------------------------------------------------------

extern "C" void kernel_launch(void* const* d_in, const int* in_sizes, int n_in,
                              void* d_out, int out_size, void* d_ws, size_t ws_size,
                              hipStream_t stream) {
    const float* x    = (const float*)d_in[0];
    const int*   erow = (const int*)  d_in[1];
    const int*   ecol = (const int*)  d_in[2];
    const float* ew   = (const float*)d_in[3];
    float* out = (float*)d_out;

    char* ws = (char*)d_ws;
    u32* edgesF = (u32*)(ws);                     // 12,800,000 B final packed edges
    u32* xb     = (u32*)(ws + 12800000);          // 12,800,000 B bf16 x (= h_0)
    u32* hA     = (u32*)(ws + 25600000);          // 12,800,000 B
    u32* hB     = (u32*)(ws + 38400000);          // 12,800,000 B
    // padded staging aliases xb+hA+hB-head: 782*4608*8 = 28,827,648 B.
    // Dead before conv_x (writes xb) and gathers (k=0 writes hA, k=1 writes hB).
    u64* e64    = (u64*)(ws + 12800000);
    int* rp     = (int*)(ws + 51200000);          //    400,000 B
    int* bcur   = (int*)(ws + 51600000);          //      3,128 B
    int* bbase  = (int*)(ws + 51604096);          //      3,128 B

    dim3 blk(256);
    dim3 gChunk(NCHB);                            // 391
    dim3 gConv((NN * 8 + 255) / 256);             // 3125
    dim3 gG(NN / 4);                              // 25000 blocks, 1 wave/node

    init_cur<<<dim3((NBKT + 255) / 256), blk, 0, stream>>>(bcur);
    bucket_scatter<<<gChunk, blk, 0, stream>>>(erow, ecol, ew, bcur, e64);
    scan_buckets<<<1, 1024, 0, stream>>>(bcur, bbase);
    build_rows<<<NBKT, dim3(BRT), 0, stream>>>(e64, bcur, bbase, edgesF, rp);
    conv_x<<<gConv, blk, 0, stream>>>(x, xb);     // after build_rows: xb aliased e64

    // k=0 reads xb; then ping-pong hA/hB; k=9 writes f32 out
    for (int k = 0; k < K_STEPS; ++k) {
        const u32* src = (k == 0) ? xb : ((k & 1) ? hA : hB);
        u32* dst = (k & 1) ? hB : hA;
        int fin = (k == K_STEPS - 1);
        gather_step<<<gG, blk, 0, stream>>>(rp, edgesF, src, xb,
                                            fin ? nullptr : dst,
                                            fin ? out : nullptr, fin);
    }
}